// Round 5
// baseline (2198.103 us; speedup 1.0000x reference)
//
#include <hip/hip_runtime.h>
#include <hip/hip_bf16.h>
#include <math.h>

#define BM 128
#define BN 128
#define BK 64

typedef __attribute__((ext_vector_type(8))) short short8;
typedef __attribute__((ext_vector_type(4))) float floatx4;

__device__ __forceinline__ void gl2lds16(const void* g, void* l) {
  __builtin_amdgcn_global_load_lds(
      (const __attribute__((address_space(1))) void*)g,
      (__attribute__((address_space(3))) void*)l, 16, 0, 0);
}

__device__ __forceinline__ float gelu_f(float v) {
  return 0.5f * v * (1.0f + erff(v * 0.70710678118654752f));
}

// ---------------- small prep kernels ----------------

// softmax over 48x48, mask > 0.01, has_nb
__global__ void adj_k(const float* __restrict__ lw, float* __restrict__ adj_m,
                      int* __restrict__ has_nb) {
  int i = threadIdx.x;
  if (i >= 48) return;
  float row[48];
  float mx = -1e30f;
#pragma unroll
  for (int j = 0; j < 48; ++j) { row[j] = lw[i * 48 + j]; mx = fmaxf(mx, row[j]); }
  float s = 0.f;
#pragma unroll
  for (int j = 0; j < 48; ++j) { row[j] = expf(row[j] - mx); s += row[j]; }
  float inv = 1.0f / s;
  int any = 0;
#pragma unroll
  for (int j = 0; j < 48; ++j) {
    float a = row[j] * inv;
    int nb = a > 0.01f;
    any |= nb;
    adj_m[i * 48 + j] = nb ? a : 0.0f;
  }
  has_nb[i] = any;
}

// dst (N x K, bf16) = transpose(src (K x N, fp32)); one 32x32 tile per block.
__device__ __forceinline__ void trans_tile(const float* __restrict__ src,
                                           __hip_bfloat16* __restrict__ dst,
                                           int K, int N) {
  __shared__ float tile[32][33];
  int tx = threadIdx.x & 31, ty = threadIdx.x >> 5;
  int n0 = blockIdx.x * 32, k0 = blockIdx.y * 32;
#pragma unroll
  for (int i = 0; i < 32; i += 8)
    tile[ty + i][tx] = src[(size_t)(k0 + ty + i) * N + n0 + tx];
  __syncthreads();
#pragma unroll
  for (int i = 0; i < 32; i += 8)
    dst[(size_t)(n0 + ty + i) * K + k0 + tx] = __float2bfloat16(tile[tx][ty + i]);
}

// three 512x512 weights, blockIdx.z picks which
__global__ __launch_bounds__(256) void trans3_k(const float* s0, __hip_bfloat16* d0,
                                                const float* s1, __hip_bfloat16* d1,
                                                const float* s2, __hip_bfloat16* d2) {
  int z = blockIdx.z;
  const float* s = (z == 0) ? s0 : (z == 1) ? s1 : s2;
  __hip_bfloat16* d = (z == 0) ? d0 : (z == 1) ? d1 : d2;
  trans_tile(s, d, 512, 512);
}

// two 1024x512 weights (K=1024), blockIdx.z picks which
__global__ __launch_bounds__(256) void trans2_k(const float* s0, __hip_bfloat16* d0,
                                                const float* s1, __hip_bfloat16* d1) {
  int z = blockIdx.z;
  const float* s = (z == 0) ? s0 : s1;
  __hip_bfloat16* d = (z == 0) ? d0 : d1;
  trans_tile(s, d, 1024, 512);
}

// x fp32 (M x 512) -> bf16 into gate_in[:, :512] (row stride 1024)
__global__ __launch_bounds__(256) void cast_x_k(const float* __restrict__ x,
                                                __hip_bfloat16* __restrict__ gate_in) {
  size_t e = ((size_t)blockIdx.x * 256 + threadIdx.x) * 8;
  size_t row = e >> 9;
  size_t col = e & 511;
  float4 v0 = *(const float4*)(x + e);
  float4 v1 = *(const float4*)(x + e + 4);
  float vv[8] = {v0.x, v0.y, v0.z, v0.w, v1.x, v1.y, v1.z, v1.w};
  __align__(16) __hip_bfloat16 tmp[8];
#pragma unroll
  for (int i = 0; i < 8; ++i) tmp[i] = __float2bfloat16(vv[i]);
  *(float4*)(gate_in + row * 1024 + col) = *(float4*)tmp;
}

// Fused LayerNorm+gelu+adjacency-contraction. One block per batch b.
// h16: M x 512 bf16. Writes x_t -> edge_in[:, :512], weighted -> edge_in[:, 512:].
__global__ __launch_bounds__(256) void lnw_k(const __hip_bfloat16* __restrict__ h16,
                                             const float* __restrict__ ln_g,
                                             const float* __restrict__ ln_b,
                                             const float* __restrict__ adj_m,
                                             __hip_bfloat16* __restrict__ edge_in) {
  __shared__ __align__(16) unsigned short xs[48 * 512];
  int b = blockIdx.x, tid = threadIdx.x;
  const __hip_bfloat16* hb = h16 + (size_t)b * 48 * 512;
  // 48*512 bf16 = 3072 chunks of 16B -> 12 iterations of 256 threads
#pragma unroll
  for (int it = 0; it < 12; ++it) {
    int ch = it * 256 + tid;
    *(float4*)&xs[ch * 8] = *(const float4*)(hb + (size_t)ch * 8);
  }
  __syncthreads();
  int wave = tid >> 6, lane = tid & 63;
  float4 g0 = *(const float4*)(ln_g + lane * 8);
  float4 g1 = *(const float4*)(ln_g + lane * 8 + 4);
  float4 c0 = *(const float4*)(ln_b + lane * 8);
  float4 c1 = *(const float4*)(ln_b + lane * 8 + 4);
  float gw[8] = {g0.x, g0.y, g0.z, g0.w, g1.x, g1.y, g1.z, g1.w};
  float bw[8] = {c0.x, c0.y, c0.z, c0.w, c1.x, c1.y, c1.z, c1.w};
  for (int rr = 0; rr < 12; ++rr) {
    int row = wave * 12 + rr;
    __align__(16) __hip_bfloat16 hv[8];
    *(float4*)hv = *(float4*)&xs[row * 512 + lane * 8];
    float vv[8];
    float s = 0.f, sq = 0.f;
#pragma unroll
    for (int i = 0; i < 8; ++i) {
      vv[i] = __bfloat162float(hv[i]);
      s += vv[i];
      sq += vv[i] * vv[i];
    }
#pragma unroll
    for (int off = 32; off > 0; off >>= 1) {
      s += __shfl_down(s, off);
      sq += __shfl_down(sq, off);
    }
    s = __shfl(s, 0);
    sq = __shfl(sq, 0);
    float mu = s * (1.0f / 512.0f);
    float var = sq * (1.0f / 512.0f) - mu * mu;
    float inv = rsqrtf(var + 1e-5f);
    __align__(16) __hip_bfloat16 tmp[8];
#pragma unroll
    for (int i = 0; i < 8; ++i) {
      float t = (vv[i] - mu) * inv * gw[i] + bw[i];
      tmp[i] = __float2bfloat16(gelu_f(t));
    }
    *(float4*)&xs[row * 512 + lane * 8] = *(float4*)tmp;
    *(float4*)(edge_in + (size_t)(b * 48 + row) * 1024 + lane * 8) = *(float4*)tmp;
  }
  __syncthreads();
  // weighted[i,d] = sum_j adj[i,j] * x_t[j,d]
  int d0 = tid;  // covers d0 and d0+256
  float xr0[48], xr1[48];
#pragma unroll
  for (int j = 0; j < 48; ++j) {
    xr0[j] = __bfloat162float(*(const __hip_bfloat16*)&xs[j * 512 + d0]);
    xr1[j] = __bfloat162float(*(const __hip_bfloat16*)&xs[j * 512 + d0 + 256]);
  }
  for (int i = 0; i < 48; ++i) {
    float a0 = 0.f, a1 = 0.f;
#pragma unroll
    for (int j = 0; j < 48; ++j) {
      float w = adj_m[i * 48 + j];
      a0 += w * xr0[j];
      a1 += w * xr1[j];
    }
    __hip_bfloat16* outp = edge_in + (size_t)(b * 48 + i) * 1024 + 512;
    outp[d0] = __float2bfloat16(a0);
    outp[d0 + 256] = __float2bfloat16(a1);
  }
}

// ---------------- main GEMM (m97 structure, XCD-swizzled) ----------------
// C(M x 512) = A(M x K, row stride lda, bf16) * Bt(N x K, bf16)^T with epilogue.
// MODE 0: out_b[ld 512] = bf16(acc + bias)            (h)
// MODE 1: out_b[ld 512] = bf16(gelu(acc + bias))      (t2)
// MODE 2: out_b[ld 1024] = bf16(has_nb ? acc+bias : xt)  (messages)
template <int MODE>
__global__ __launch_bounds__(256, 2) void gemm_k(
    const __hip_bfloat16* __restrict__ A, int lda, int K,
    const __hip_bfloat16* __restrict__ Bt,
    const float* __restrict__ bias,
    __hip_bfloat16* __restrict__ out_b,
    const __hip_bfloat16* __restrict__ xt,
    const int* __restrict__ has_nb) {
  __shared__ __align__(16) unsigned short As[BM * BK];
  __shared__ __align__(16) unsigned short Bs[BN * BK];
  const int tid = threadIdx.x;
  // XCD-aware chunked swizzle: grid = (4, 1536), nwg = 6144 = 8 * 768.
  int bid = blockIdx.y * 4 + blockIdx.x;
  int wg = (bid & 7) * 768 + (bid >> 3);
  const int tileM = (wg >> 2) * BM;
  const int tileN = (wg & 3) * BN;
  const int wave = tid >> 6, lane = tid & 63;
  const int wm = (wave >> 1) * 64, wn = (wave & 1) * 64;
  const int m16 = lane & 15, quad = lane >> 4;
  const int kq = quad * 8;

  floatx4 acc[4][4];
#pragma unroll
  for (int i = 0; i < 4; ++i)
#pragma unroll
    for (int j = 0; j < 4; ++j) acc[i][j] = (floatx4)0.0f;

  for (int k0 = 0; k0 < K; k0 += BK) {
#pragma unroll
    for (int it = 0; it < 4; ++it) {
      int chunk = it * 256 + tid;      // 1024 chunks of 16B = 128x64 bf16
      int r = chunk >> 3, c = chunk & 7;
      gl2lds16(A + (size_t)(tileM + r) * lda + k0 + c * 8, &As[chunk * 8]);
    }
#pragma unroll
    for (int it = 0; it < 4; ++it) {
      int chunk = it * 256 + tid;
      int r = chunk >> 3, c = chunk & 7;
      gl2lds16(Bt + (size_t)(tileN + r) * K + k0 + c * 8, &Bs[chunk * 8]);
    }
    __syncthreads();
#pragma unroll
    for (int kk = 0; kk < BK; kk += 32) {
      short8 af[4], bfr[4];
#pragma unroll
      for (int i = 0; i < 4; ++i)
        af[i] = *(const short8*)&As[(wm + i * 16 + m16) * BK + kk + kq];
#pragma unroll
      for (int i = 0; i < 4; ++i)
        bfr[i] = *(const short8*)&Bs[(wn + i * 16 + m16) * BK + kk + kq];
#pragma unroll
      for (int mi = 0; mi < 4; ++mi)
#pragma unroll
        for (int ni = 0; ni < 4; ++ni)
          acc[mi][ni] = __builtin_amdgcn_mfma_f32_16x16x32_bf16(
              af[mi], bfr[ni], acc[mi][ni], 0, 0, 0);
    }
    __syncthreads();
  }

#pragma unroll
  for (int mi = 0; mi < 4; ++mi) {
#pragma unroll
    for (int ni = 0; ni < 4; ++ni) {
      int mbase = tileM + wm + mi * 16 + quad * 4;
      int n = tileN + wn + ni * 16 + m16;
      float bn = bias[n];
#pragma unroll
      for (int r = 0; r < 4; ++r) {
        int m = mbase + r;
        float v = acc[mi][ni][r] + bn;
        if constexpr (MODE == 0) {
          out_b[(size_t)m * 512 + n] = __float2bfloat16(v);
        } else if constexpr (MODE == 1) {
          out_b[(size_t)m * 512 + n] = __float2bfloat16(gelu_f(v));
        } else {
          float res = has_nb[m % 48] ? v : __bfloat162float(xt[(size_t)m * 1024 + n]);
          out_b[(size_t)m * 1024 + n] = __float2bfloat16(res);
        }
      }
    }
  }
}

// ---------------- fused gate GEMM ----------------
// acc_g = gate_in(M x 1024) @ WgT^T over K=0..1024
// acc_o = gate_in[:,512:]  @ WoT^T  == same A rows, K=512..1024 (Wo k = k-512)
// out = sigmoid(acc_g + b_g) * (acc_o + b_o) + (1-g) * x
// 512 threads, 8 waves (2 x 4), wave tile 64 x 32.
__global__ __launch_bounds__(512, 1) void gemm34_k(
    const __hip_bfloat16* __restrict__ A,     // gate_in, ld 1024
    const __hip_bfloat16* __restrict__ Btg,   // WgT: 512 x 1024
    const __hip_bfloat16* __restrict__ Bto,   // WoT: 512 x 512
    const float* __restrict__ b_g,
    const float* __restrict__ b_o,
    const float* __restrict__ x_res,
    float* __restrict__ out) {
  __shared__ __align__(16) unsigned short As[BM * BK];
  __shared__ __align__(16) unsigned short Bg[BN * BK];
  __shared__ __align__(16) unsigned short Bo[BN * BK];
  const int tid = threadIdx.x;
  int bid = blockIdx.y * 4 + blockIdx.x;
  int wg = (bid & 7) * 768 + (bid >> 3);
  const int tileM = (wg >> 2) * BM;
  const int tileN = (wg & 3) * BN;
  const int wave = tid >> 6, lane = tid & 63;
  const int wm = (wave >> 2) * 64, wn = (wave & 3) * 32;
  const int m16 = lane & 15, quad = lane >> 4;
  const int kq = quad * 8;

  floatx4 accg[4][2], acco[4][2];
#pragma unroll
  for (int i = 0; i < 4; ++i)
#pragma unroll
    for (int j = 0; j < 2; ++j) { accg[i][j] = (floatx4)0.0f; acco[i][j] = (floatx4)0.0f; }

  for (int k0 = 0; k0 < 1024; k0 += BK) {
#pragma unroll
    for (int it = 0; it < 2; ++it) {
      int chunk = it * 512 + tid;      // 1024 chunks of 16B
      int r = chunk >> 3, c = chunk & 7;
      gl2lds16(A + (size_t)(tileM + r) * 1024 + k0 + c * 8, &As[chunk * 8]);
      gl2lds16(Btg + (size_t)(tileN + r) * 1024 + k0 + c * 8, &Bg[chunk * 8]);
      if (k0 >= 512)
        gl2lds16(Bto + (size_t)(tileN + r) * 512 + (k0 - 512) + c * 8, &Bo[chunk * 8]);
    }
    __syncthreads();
#pragma unroll
    for (int kk = 0; kk < BK; kk += 32) {
      short8 af[4], bgf[2];
#pragma unroll
      for (int i = 0; i < 4; ++i)
        af[i] = *(const short8*)&As[(wm + i * 16 + m16) * BK + kk + kq];
#pragma unroll
      for (int i = 0; i < 2; ++i)
        bgf[i] = *(const short8*)&Bg[(wn + i * 16 + m16) * BK + kk + kq];
#pragma unroll
      for (int mi = 0; mi < 4; ++mi)
#pragma unroll
        for (int ni = 0; ni < 2; ++ni)
          accg[mi][ni] = __builtin_amdgcn_mfma_f32_16x16x32_bf16(
              af[mi], bgf[ni], accg[mi][ni], 0, 0, 0);
      if (k0 >= 512) {
        short8 bof[2];
#pragma unroll
        for (int i = 0; i < 2; ++i)
          bof[i] = *(const short8*)&Bo[(wn + i * 16 + m16) * BK + kk + kq];
#pragma unroll
        for (int mi = 0; mi < 4; ++mi)
#pragma unroll
          for (int ni = 0; ni < 2; ++ni)
            acco[mi][ni] = __builtin_amdgcn_mfma_f32_16x16x32_bf16(
                af[mi], bof[ni], acco[mi][ni], 0, 0, 0);
      }
    }
    __syncthreads();
  }

#pragma unroll
  for (int mi = 0; mi < 4; ++mi) {
#pragma unroll
    for (int ni = 0; ni < 2; ++ni) {
      int mbase = tileM + wm + mi * 16 + quad * 4;
      int n = tileN + wn + ni * 16 + m16;
      float bgn = b_g[n], bon = b_o[n];
#pragma unroll
      for (int r = 0; r < 4; ++r) {
        int m = mbase + r;
        float vg = accg[mi][ni][r] + bgn;
        float vo = acco[mi][ni][r] + bon;
        float g = 1.0f / (1.0f + expf(-vg));
        size_t idx = (size_t)m * 512 + n;
        out[idx] = g * vo + (1.0f - g) * x_res[idx];
      }
    }
  }
}

// ---------------- launch ----------------

extern "C" void kernel_launch(void* const* d_in, const int* in_sizes, int n_in,
                              void* d_out, int out_size, void* d_ws, size_t ws_size,
                              hipStream_t stream) {
  const float* x    = (const float*)d_in[0];
  const float* lw   = (const float*)d_in[1];
  const float* W_nt = (const float*)d_in[2];
  const float* b_nt = (const float*)d_in[3];
  const float* ln_g = (const float*)d_in[4];
  const float* ln_b = (const float*)d_in[5];
  const float* W_e1 = (const float*)d_in[6];
  const float* b_e1 = (const float*)d_in[7];
  const float* W_e2 = (const float*)d_in[8];
  const float* b_e2 = (const float*)d_in[9];
  const float* W_o  = (const float*)d_in[10];
  const float* b_o  = (const float*)d_in[11];
  const float* W_g  = (const float*)d_in[12];
  const float* b_g  = (const float*)d_in[13];
  float* out = (float*)d_out;

  const int M = 4096 * 48;  // 196608
  char* ws = (char*)d_ws;
  const size_t SZ_GI = (size_t)M * 1024 * 2;  // 402653184
  __hip_bfloat16* gate_in = (__hip_bfloat16*)(ws);
  __hip_bfloat16* edge_in = (__hip_bfloat16*)(ws + SZ_GI);
  __hip_bfloat16* h16 = (__hip_bfloat16*)(ws + 2 * SZ_GI);    // M x 512 bf16
  __hip_bfloat16* t2 = (__hip_bfloat16*)(ws + 3 * SZ_GI);     // M x 512 bf16
  char* wts = ws + 3 * SZ_GI + (size_t)M * 512 * 2;
  __hip_bfloat16* WntT = (__hip_bfloat16*)wts;
  __hip_bfloat16* We1T = WntT + 512 * 512;
  __hip_bfloat16* We2T = We1T + 512 * 1024;
  __hip_bfloat16* WoT  = We2T + 512 * 512;
  __hip_bfloat16* WgT  = WoT + 512 * 512;
  float* adj_m = (float*)(WgT + 512 * 1024);
  int* has_nb = (int*)(adj_m + 48 * 48);

  adj_k<<<1, 64, 0, stream>>>(lw, adj_m, has_nb);
  trans3_k<<<dim3(16, 16, 3), 256, 0, stream>>>(W_nt, WntT, W_e2, We2T, W_o, WoT);
  trans2_k<<<dim3(16, 32, 2), 256, 0, stream>>>(W_e1, We1T, W_g, WgT);
  cast_x_k<<<(M * 512) / (256 * 8), 256, 0, stream>>>(x, gate_in);

  dim3 gg(512 / BN, M / BM);
  // h = x @ W_nt + b_nt  (bf16)
  gemm_k<0><<<gg, 256, 0, stream>>>(gate_in, 1024, 512, WntT, b_nt, h16,
                                    nullptr, nullptr);
  // x_t = gelu(LN(h)) -> edge_in[:, :512]; weighted -> edge_in[:, 512:]
  lnw_k<<<4096, 256, 0, stream>>>(h16, ln_g, ln_b, adj_m, edge_in);
  // t2 = gelu(edge_in @ W_e1 + b_e1)
  gemm_k<1><<<gg, 256, 0, stream>>>(edge_in, 1024, 1024, We1T, b_e1, t2,
                                    nullptr, nullptr);
  // messages = (has_nb ? t2 @ W_e2 + b_e2 : x_t) -> gate_in[:, 512:]
  gemm_k<2><<<gg, 256, 0, stream>>>(t2, 512, 512, We2T, b_e2, gate_in + 512,
                                    edge_in, has_nb);
  // fused: g = sigmoid(gate_in @ W_g + b_g); o = messages @ W_o + b_o;
  //        out = g*o + (1-g)*x
  gemm34_k<<<gg, 512, 0, stream>>>(gate_in, WgT, WoT, b_g, b_o, x, out);
}

// Round 8
// 2165.638 us; speedup vs baseline: 1.0150x; 1.0150x over previous
//
#include <hip/hip_runtime.h>
#include <hip/hip_bf16.h>
#include <math.h>

#define BM 128
#define BN 128
#define BK 64

typedef __attribute__((ext_vector_type(8))) short short8;
typedef __attribute__((ext_vector_type(4))) float floatx4;

__device__ __forceinline__ void gl2lds16(const void* g, void* l) {
  __builtin_amdgcn_global_load_lds(
      (const __attribute__((address_space(1))) void*)g,
      (__attribute__((address_space(3))) void*)l, 16, 0, 0);
}

__device__ __forceinline__ float gelu_f(float v) {
  return 0.5f * v * (1.0f + erff(v * 0.70710678118654752f));
}

// ---------------- small prep kernels ----------------

// softmax over 48x48, mask > 0.01, has_nb
__global__ void adj_k(const float* __restrict__ lw, float* __restrict__ adj_m,
                      int* __restrict__ has_nb) {
  int i = threadIdx.x;
  if (i >= 48) return;
  float row[48];
  float mx = -1e30f;
#pragma unroll
  for (int j = 0; j < 48; ++j) { row[j] = lw[i * 48 + j]; mx = fmaxf(mx, row[j]); }
  float s = 0.f;
#pragma unroll
  for (int j = 0; j < 48; ++j) { row[j] = expf(row[j] - mx); s += row[j]; }
  float inv = 1.0f / s;
  int any = 0;
#pragma unroll
  for (int j = 0; j < 48; ++j) {
    float a = row[j] * inv;
    int nb = a > 0.01f;
    any |= nb;
    adj_m[i * 48 + j] = nb ? a : 0.0f;
  }
  has_nb[i] = any;
}

// dst (N x K, bf16) = transpose(src (K x N, fp32)); one 32x32 tile per block.
__device__ __forceinline__ void trans_tile(const float* __restrict__ src,
                                           __hip_bfloat16* __restrict__ dst,
                                           int K, int N) {
  __shared__ float tile[32][33];
  int tx = threadIdx.x & 31, ty = threadIdx.x >> 5;
  int n0 = blockIdx.x * 32, k0 = blockIdx.y * 32;
#pragma unroll
  for (int i = 0; i < 32; i += 8)
    tile[ty + i][tx] = src[(size_t)(k0 + ty + i) * N + n0 + tx];
  __syncthreads();
#pragma unroll
  for (int i = 0; i < 32; i += 8)
    dst[(size_t)(n0 + ty + i) * K + k0 + tx] = __float2bfloat16(tile[tx][ty + i]);
}

// three 512x512 weights, blockIdx.z picks which
__global__ __launch_bounds__(256) void trans3_k(const float* s0, __hip_bfloat16* d0,
                                                const float* s1, __hip_bfloat16* d1,
                                                const float* s2, __hip_bfloat16* d2) {
  int z = blockIdx.z;
  const float* s = (z == 0) ? s0 : (z == 1) ? s1 : s2;
  __hip_bfloat16* d = (z == 0) ? d0 : (z == 1) ? d1 : d2;
  trans_tile(s, d, 512, 512);
}

// two 1024x512 weights (K=1024), blockIdx.z picks which
__global__ __launch_bounds__(256) void trans2_k(const float* s0, __hip_bfloat16* d0,
                                                const float* s1, __hip_bfloat16* d1) {
  int z = blockIdx.z;
  const float* s = (z == 0) ? s0 : s1;
  __hip_bfloat16* d = (z == 0) ? d0 : d1;
  trans_tile(s, d, 1024, 512);
}

// x fp32 (M x 512) -> bf16 into gate_in[:, :512] (row stride 1024)
__global__ __launch_bounds__(256) void cast_x_k(const float* __restrict__ x,
                                                __hip_bfloat16* __restrict__ gate_in) {
  size_t e = ((size_t)blockIdx.x * 256 + threadIdx.x) * 8;
  size_t row = e >> 9;
  size_t col = e & 511;
  float4 v0 = *(const float4*)(x + e);
  float4 v1 = *(const float4*)(x + e + 4);
  float vv[8] = {v0.x, v0.y, v0.z, v0.w, v1.x, v1.y, v1.z, v1.w};
  __align__(16) __hip_bfloat16 tmp[8];
#pragma unroll
  for (int i = 0; i < 8; ++i) tmp[i] = __float2bfloat16(vv[i]);
  *(float4*)(gate_in + row * 1024 + col) = *(float4*)tmp;
}

// Fused LayerNorm+gelu+adjacency-contraction. One block per batch b.
// h16: M x 512 bf16. Writes x_t -> edge_in[:, :512], weighted -> edge_in[:, 512:].
__global__ __launch_bounds__(256) void lnw_k(const __hip_bfloat16* __restrict__ h16,
                                             const float* __restrict__ ln_g,
                                             const float* __restrict__ ln_b,
                                             const float* __restrict__ adj_m,
                                             __hip_bfloat16* __restrict__ edge_in) {
  __shared__ __align__(16) unsigned short xs[48 * 512];
  int b = blockIdx.x, tid = threadIdx.x;
  const __hip_bfloat16* hb = h16 + (size_t)b * 48 * 512;
  // 48*512 bf16 = 3072 chunks of 16B -> 12 iterations of 256 threads
#pragma unroll
  for (int it = 0; it < 12; ++it) {
    int ch = it * 256 + tid;
    *(float4*)&xs[ch * 8] = *(const float4*)(hb + (size_t)ch * 8);
  }
  __syncthreads();
  int wave = tid >> 6, lane = tid & 63;
  float4 g0 = *(const float4*)(ln_g + lane * 8);
  float4 g1 = *(const float4*)(ln_g + lane * 8 + 4);
  float4 c0 = *(const float4*)(ln_b + lane * 8);
  float4 c1 = *(const float4*)(ln_b + lane * 8 + 4);
  float gw[8] = {g0.x, g0.y, g0.z, g0.w, g1.x, g1.y, g1.z, g1.w};
  float bw[8] = {c0.x, c0.y, c0.z, c0.w, c1.x, c1.y, c1.z, c1.w};
  for (int rr = 0; rr < 12; ++rr) {
    int row = wave * 12 + rr;
    __align__(16) __hip_bfloat16 hv[8];
    *(float4*)hv = *(float4*)&xs[row * 512 + lane * 8];
    float vv[8];
    float s = 0.f, sq = 0.f;
#pragma unroll
    for (int i = 0; i < 8; ++i) {
      vv[i] = __bfloat162float(hv[i]);
      s += vv[i];
      sq += vv[i] * vv[i];
    }
#pragma unroll
    for (int off = 32; off > 0; off >>= 1) {
      s += __shfl_down(s, off);
      sq += __shfl_down(sq, off);
    }
    s = __shfl(s, 0);
    sq = __shfl(sq, 0);
    float mu = s * (1.0f / 512.0f);
    float var = sq * (1.0f / 512.0f) - mu * mu;
    float inv = rsqrtf(var + 1e-5f);
    __align__(16) __hip_bfloat16 tmp[8];
#pragma unroll
    for (int i = 0; i < 8; ++i) {
      float t = (vv[i] - mu) * inv * gw[i] + bw[i];
      tmp[i] = __float2bfloat16(gelu_f(t));
    }
    *(float4*)&xs[row * 512 + lane * 8] = *(float4*)tmp;
    *(float4*)(edge_in + (size_t)(b * 48 + row) * 1024 + lane * 8) = *(float4*)tmp;
  }
  __syncthreads();
  // weighted[i,d] = sum_j adj[i,j] * x_t[j,d]
  int d0 = tid;  // covers d0 and d0+256
  float xr0[48], xr1[48];
#pragma unroll
  for (int j = 0; j < 48; ++j) {
    xr0[j] = __bfloat162float(*(const __hip_bfloat16*)&xs[j * 512 + d0]);
    xr1[j] = __bfloat162float(*(const __hip_bfloat16*)&xs[j * 512 + d0 + 256]);
  }
  for (int i = 0; i < 48; ++i) {
    float a0 = 0.f, a1 = 0.f;
#pragma unroll
    for (int j = 0; j < 48; ++j) {
      float w = adj_m[i * 48 + j];
      a0 += w * xr0[j];
      a1 += w * xr1[j];
    }
    __hip_bfloat16* outp = edge_in + (size_t)(b * 48 + i) * 1024 + 512;
    outp[d0] = __float2bfloat16(a0);
    outp[d0 + 256] = __float2bfloat16(a1);
  }
}

// ---------------- main GEMM (m97 structure, XCD-swizzled) ----------------
// C(M x 512) = A(M x K, row stride lda, bf16) * Bt(N x K, bf16)^T with epilogue.
// MODE 0: out_b[ld 512] = bf16(acc + bias)            (h)
// MODE 1: out_b[ld 512] = bf16(gelu(acc + bias))      (t2)
// MODE 2: out_b[ld 1024] = bf16(has_nb ? acc+bias : xt)  (messages)
template <int MODE>
__global__ __launch_bounds__(256, 2) void gemm_k(
    const __hip_bfloat16* __restrict__ A, int lda, int K,
    const __hip_bfloat16* __restrict__ Bt,
    const float* __restrict__ bias,
    __hip_bfloat16* __restrict__ out_b,
    const __hip_bfloat16* __restrict__ xt,
    const int* __restrict__ has_nb) {
  __shared__ __align__(16) unsigned short As[BM * BK];
  __shared__ __align__(16) unsigned short Bs[BN * BK];
  const int tid = threadIdx.x;
  // XCD-aware chunked swizzle: grid = (4, 1536), nwg = 6144 = 8 * 768.
  int bid = blockIdx.y * 4 + blockIdx.x;
  int wg = (bid & 7) * 768 + (bid >> 3);
  const int tileM = (wg >> 2) * BM;
  const int tileN = (wg & 3) * BN;
  const int wave = tid >> 6, lane = tid & 63;
  const int wm = (wave >> 1) * 64, wn = (wave & 1) * 64;
  const int m16 = lane & 15, quad = lane >> 4;
  const int kq = quad * 8;

  floatx4 acc[4][4];
#pragma unroll
  for (int i = 0; i < 4; ++i)
#pragma unroll
    for (int j = 0; j < 4; ++j) acc[i][j] = (floatx4)0.0f;

  for (int k0 = 0; k0 < K; k0 += BK) {
#pragma unroll
    for (int it = 0; it < 4; ++it) {
      int chunk = it * 256 + tid;      // 1024 chunks of 16B = 128x64 bf16
      int r = chunk >> 3, c = chunk & 7;
      gl2lds16(A + (size_t)(tileM + r) * lda + k0 + c * 8, &As[chunk * 8]);
    }
#pragma unroll
    for (int it = 0; it < 4; ++it) {
      int chunk = it * 256 + tid;
      int r = chunk >> 3, c = chunk & 7;
      gl2lds16(Bt + (size_t)(tileN + r) * K + k0 + c * 8, &Bs[chunk * 8]);
    }
    __syncthreads();
#pragma unroll
    for (int kk = 0; kk < BK; kk += 32) {
      short8 af[4], bfr[4];
#pragma unroll
      for (int i = 0; i < 4; ++i)
        af[i] = *(const short8*)&As[(wm + i * 16 + m16) * BK + kk + kq];
#pragma unroll
      for (int i = 0; i < 4; ++i)
        bfr[i] = *(const short8*)&Bs[(wn + i * 16 + m16) * BK + kk + kq];
#pragma unroll
      for (int mi = 0; mi < 4; ++mi)
#pragma unroll
        for (int ni = 0; ni < 4; ++ni)
          acc[mi][ni] = __builtin_amdgcn_mfma_f32_16x16x32_bf16(
              af[mi], bfr[ni], acc[mi][ni], 0, 0, 0);
    }
    __syncthreads();
  }

#pragma unroll
  for (int mi = 0; mi < 4; ++mi) {
#pragma unroll
    for (int ni = 0; ni < 4; ++ni) {
      int mbase = tileM + wm + mi * 16 + quad * 4;
      int n = tileN + wn + ni * 16 + m16;
      float bn = bias[n];
#pragma unroll
      for (int r = 0; r < 4; ++r) {
        int m = mbase + r;
        float v = acc[mi][ni][r] + bn;
        if constexpr (MODE == 0) {
          out_b[(size_t)m * 512 + n] = __float2bfloat16(v);
        } else if constexpr (MODE == 1) {
          out_b[(size_t)m * 512 + n] = __float2bfloat16(gelu_f(v));
        } else {
          float res = has_nb[m % 48] ? v : __bfloat162float(xt[(size_t)m * 1024 + n]);
          out_b[(size_t)m * 1024 + n] = __float2bfloat16(res);
        }
      }
    }
  }
}

// ---------------- fused gate GEMM (reshaped: 4 waves, 64x64/wave, dual acc) --
// acc_g = gate_in(M x 1024) @ WgT^T over K=0..1024
// acc_o = gate_in[:,512:]  @ WoT^T  == same A rows, K=512..1024 (Wo k = k-512)
// out = sigmoid(acc_g + b_g) * (acc_o + b_o) + (1-g) * x
// 256 threads, 4 waves (2 x 2), wave tile 64 x 64 — matches proven gemm_k shape
// for MFMA:ds_read density (32 MFMA per 8-12 reads vs prior 8 per 6).
__global__ __launch_bounds__(256, 2) void gemm34_k(
    const __hip_bfloat16* __restrict__ A,     // gate_in, ld 1024
    const __hip_bfloat16* __restrict__ Btg,   // WgT: 512 x 1024
    const __hip_bfloat16* __restrict__ Bto,   // WoT: 512 x 512
    const float* __restrict__ b_g,
    const float* __restrict__ b_o,
    const float* __restrict__ x_res,
    float* __restrict__ out) {
  __shared__ __align__(16) unsigned short As[BM * BK];
  __shared__ __align__(16) unsigned short Bg[BN * BK];
  __shared__ __align__(16) unsigned short Bo[BN * BK];
  const int tid = threadIdx.x;
  int bid = blockIdx.y * 4 + blockIdx.x;
  int wg = (bid & 7) * 768 + (bid >> 3);
  const int tileM = (wg >> 2) * BM;
  const int tileN = (wg & 3) * BN;
  const int wave = tid >> 6, lane = tid & 63;
  const int wm = (wave >> 1) * 64, wn = (wave & 1) * 64;
  const int m16 = lane & 15, quad = lane >> 4;
  const int kq = quad * 8;

  floatx4 accg[4][4], acco[4][4];
#pragma unroll
  for (int i = 0; i < 4; ++i)
#pragma unroll
    for (int j = 0; j < 4; ++j) { accg[i][j] = (floatx4)0.0f; acco[i][j] = (floatx4)0.0f; }

  for (int k0 = 0; k0 < 1024; k0 += BK) {
#pragma unroll
    for (int it = 0; it < 4; ++it) {
      int chunk = it * 256 + tid;      // 1024 chunks of 16B = 128x64 bf16
      int r = chunk >> 3, c = chunk & 7;
      gl2lds16(A + (size_t)(tileM + r) * 1024 + k0 + c * 8, &As[chunk * 8]);
      gl2lds16(Btg + (size_t)(tileN + r) * 1024 + k0 + c * 8, &Bg[chunk * 8]);
      if (k0 >= 512)
        gl2lds16(Bto + (size_t)(tileN + r) * 512 + (k0 - 512) + c * 8, &Bo[chunk * 8]);
    }
    __syncthreads();
#pragma unroll
    for (int kk = 0; kk < BK; kk += 32) {
      short8 af[4], bgf[4];
#pragma unroll
      for (int i = 0; i < 4; ++i)
        af[i] = *(const short8*)&As[(wm + i * 16 + m16) * BK + kk + kq];
#pragma unroll
      for (int i = 0; i < 4; ++i)
        bgf[i] = *(const short8*)&Bg[(wn + i * 16 + m16) * BK + kk + kq];
#pragma unroll
      for (int mi = 0; mi < 4; ++mi)
#pragma unroll
        for (int ni = 0; ni < 4; ++ni)
          accg[mi][ni] = __builtin_amdgcn_mfma_f32_16x16x32_bf16(
              af[mi], bgf[ni], accg[mi][ni], 0, 0, 0);
      if (k0 >= 512) {
        short8 bof[4];
#pragma unroll
        for (int i = 0; i < 4; ++i)
          bof[i] = *(const short8*)&Bo[(wn + i * 16 + m16) * BK + kk + kq];
#pragma unroll
        for (int mi = 0; mi < 4; ++mi)
#pragma unroll
          for (int ni = 0; ni < 4; ++ni)
            acco[mi][ni] = __builtin_amdgcn_mfma_f32_16x16x32_bf16(
                af[mi], bof[ni], acco[mi][ni], 0, 0, 0);
      }
    }
    __syncthreads();
  }

#pragma unroll
  for (int mi = 0; mi < 4; ++mi) {
#pragma unroll
    for (int ni = 0; ni < 4; ++ni) {
      int mbase = tileM + wm + mi * 16 + quad * 4;
      int n = tileN + wn + ni * 16 + m16;
      float bgn = b_g[n], bon = b_o[n];
#pragma unroll
      for (int r = 0; r < 4; ++r) {
        int m = mbase + r;
        float vg = accg[mi][ni][r] + bgn;
        float vo = acco[mi][ni][r] + bon;
        float g = 1.0f / (1.0f + expf(-vg));
        size_t idx = (size_t)m * 512 + n;
        out[idx] = g * vo + (1.0f - g) * x_res[idx];
      }
    }
  }
}

// ---------------- launch ----------------

extern "C" void kernel_launch(void* const* d_in, const int* in_sizes, int n_in,
                              void* d_out, int out_size, void* d_ws, size_t ws_size,
                              hipStream_t stream) {
  const float* x    = (const float*)d_in[0];
  const float* lw   = (const float*)d_in[1];
  const float* W_nt = (const float*)d_in[2];
  const float* b_nt = (const float*)d_in[3];
  const float* ln_g = (const float*)d_in[4];
  const float* ln_b = (const float*)d_in[5];
  const float* W_e1 = (const float*)d_in[6];
  const float* b_e1 = (const float*)d_in[7];
  const float* W_e2 = (const float*)d_in[8];
  const float* b_e2 = (const float*)d_in[9];
  const float* W_o  = (const float*)d_in[10];
  const float* b_o  = (const float*)d_in[11];
  const float* W_g  = (const float*)d_in[12];
  const float* b_g  = (const float*)d_in[13];
  float* out = (float*)d_out;

  const int M = 4096 * 48;  // 196608
  char* ws = (char*)d_ws;
  const size_t SZ_GI = (size_t)M * 1024 * 2;  // 402653184
  __hip_bfloat16* gate_in = (__hip_bfloat16*)(ws);
  __hip_bfloat16* edge_in = (__hip_bfloat16*)(ws + SZ_GI);
  __hip_bfloat16* h16 = (__hip_bfloat16*)(ws + 2 * SZ_GI);    // M x 512 bf16
  __hip_bfloat16* t2 = (__hip_bfloat16*)(ws + 3 * SZ_GI);     // M x 512 bf16
  char* wts = ws + 3 * SZ_GI + (size_t)M * 512 * 2;
  __hip_bfloat16* WntT = (__hip_bfloat16*)wts;
  __hip_bfloat16* We1T = WntT + 512 * 512;
  __hip_bfloat16* We2T = We1T + 512 * 1024;
  __hip_bfloat16* WoT  = We2T + 512 * 512;
  __hip_bfloat16* WgT  = WoT + 512 * 512;
  float* adj_m = (float*)(WgT + 512 * 1024);
  int* has_nb = (int*)(adj_m + 48 * 48);

  adj_k<<<1, 64, 0, stream>>>(lw, adj_m, has_nb);
  trans3_k<<<dim3(16, 16, 3), 256, 0, stream>>>(W_nt, WntT, W_e2, We2T, W_o, WoT);
  trans2_k<<<dim3(16, 32, 2), 256, 0, stream>>>(W_e1, We1T, W_g, WgT);
  cast_x_k<<<(M * 512) / (256 * 8), 256, 0, stream>>>(x, gate_in);

  dim3 gg(512 / BN, M / BM);
  // h = x @ W_nt + b_nt  (bf16)
  gemm_k<0><<<gg, 256, 0, stream>>>(gate_in, 1024, 512, WntT, b_nt, h16,
                                    nullptr, nullptr);
  // x_t = gelu(LN(h)) -> edge_in[:, :512]; weighted -> edge_in[:, 512:]
  lnw_k<<<4096, 256, 0, stream>>>(h16, ln_g, ln_b, adj_m, edge_in);
  // t2 = gelu(edge_in @ W_e1 + b_e1)
  gemm_k<1><<<gg, 256, 0, stream>>>(edge_in, 1024, 1024, We1T, b_e1, t2,
                                    nullptr, nullptr);
  // messages = (has_nb ? t2 @ W_e2 + b_e2 : x_t) -> gate_in[:, 512:]
  gemm_k<2><<<gg, 256, 0, stream>>>(t2, 512, 512, We2T, b_e2, gate_in + 512,
                                    edge_in, has_nb);
  // fused: g = sigmoid(gate_in @ W_g + b_g); o = messages @ W_o + b_o;
  //        out = g*o + (1-g)*x
  gemm34_k<<<gg, 256, 0, stream>>>(gate_in, WgT, WoT, b_g, b_o, x, out);
}